// Round 5
// baseline (436.118 us; speedup 1.0000x reference)
//
#include <hip/hip_runtime.h>

#define TT 128
#define BB 32
#define NN (TT*BB)   // 4096

typedef float f4 __attribute__((ext_vector_type(4)));
typedef float f32x4 __attribute__((ext_vector_type(4)));
typedef short s8 __attribute__((ext_vector_type(8)));
typedef short bf16x8 __attribute__((ext_vector_type(8)));
typedef short s4v __attribute__((ext_vector_type(4)));

__device__ __forceinline__ float bf2f(unsigned short u){
  union{unsigned int i; float f;} x; x.i = ((unsigned int)u)<<16; return x.f;
}
__device__ __forceinline__ unsigned short f2bf(float f){
  union{float ff; unsigned int i;} x; x.ff=f;
  unsigned int r = x.i + 0x7FFFu + ((x.i>>16)&1u);
  return (unsigned short)(r>>16);
}
// NaN-safe fast sigmoid/tanh
__device__ __forceinline__ float fsig(float x){
  return __builtin_amdgcn_rcpf(1.f + __expf(-x));
}
__device__ __forceinline__ float ftanh(float x){
  return 1.f - 2.f*__builtin_amdgcn_rcpf(1.f + __expf(2.f*x));
}
// async global(16B contiguous per lane) -> LDS (wave-uniform base + lane*16)
__device__ __forceinline__ void gload_lds16(const void* g, void* lds){
  __builtin_amdgcn_global_load_lds(
    (const __attribute__((address_space(1))) unsigned int*)g,
    (__attribute__((address_space(3))) unsigned int*)lds, 16, 0, 0);
}

// ================= weight prep =============================================
__global__ __launch_bounds__(256) void prep_w1(const float* __restrict__ W1,
    unsigned short* __restrict__ w1c){
  int i = blockIdx.x*256 + threadIdx.x;       // 4096
  int co = i >> 6; int k = i & 63;
  w1c[i] = (co < 32) ? f2bf(W1[co*64 + k] * (1.f/255.f)) : (unsigned short)0;
}
__global__ __launch_bounds__(256) void prep_w2(const float* __restrict__ W2,
    unsigned short* __restrict__ w2c){
  int i = blockIdx.x*256 + threadIdx.x;       // 32768
  int co = i >> 9; int rem = i & 511; int khw = rem >> 5; int ci = rem & 31;
  w2c[i] = f2bf(W2[(co*32 + ci)*16 + khw]);
}
__global__ __launch_bounds__(256) void prep_w3(const float* __restrict__ W3,
    unsigned short* __restrict__ w3c){
  int i = blockIdx.x*256 + threadIdx.x;       // 36864
  int co = i/576; int rem = i - co*576; int khw = rem >> 6; int ci = rem & 63;
  w3c[i] = f2bf(W3[(co*64 + ci)*9 + khw]);
}
__global__ __launch_bounds__(256) void prep_wfc(const float* __restrict__ Wfc,
    unsigned short* __restrict__ wfcc){
  int i = blockIdx.x*256 + threadIdx.x;       // 1605632
  int nn = i/3136; int rem = i - nn*3136; int sp = rem >> 6; int ci = rem & 63;
  wfcc[i] = f2bf(Wfc[nn*3136 + ci*49 + sp]);
}
__global__ __launch_bounds__(256) void prep_wih(const float* __restrict__ W_ih,
    unsigned short* __restrict__ wihc){
  int i = blockIdx.x*256 + threadIdx.x;       // 262144
  wihc[i] = f2bf(W_ih[i]);
}
__global__ __launch_bounds__(256) void prep_whh(const float* __restrict__ W_hh,
    unsigned short* __restrict__ whhc){
  int i = blockIdx.x*256 + threadIdx.x;       // 65536
  whhc[i] = f2bf(W_hh[i]);
}
__global__ __launch_bounds__(256) void prep_x(const float* __restrict__ x,
    unsigned short* __restrict__ xb){
  int i = blockIdx.x*256 + threadIdx.x;       // 3,612,672
  f4 v0 = *(const f4*)(x + (size_t)i*8);
  f4 v1 = *(const f4*)(x + (size_t)i*8 + 4);
  s8 o;
  #pragma unroll
  for(int j=0;j<4;j++){ o[j] = (short)f2bf(v0[j]); o[4+j] = (short)f2bf(v1[j]); }
  *(s8*)&xb[(size_t)i*8] = o;
}

// ================= unified MFMA GEMM =======================================
// C[M,N] = act(A[M,K]*B[N,K]^T + bias1 (+bias2)); A bf16 (gathered), B bf16 [N][K].
// BM=128, BN=64, BK=32. 256 threads = 4 waves (2x2), wave tile 64x32.
template<int MODE, int OUTBF16, int RELU>
__global__ __launch_bounds__(256) void mgemm_k(
    const unsigned short* __restrict__ A, const unsigned short* __restrict__ B,
    const float* __restrict__ bias1, const float* __restrict__ bias2,
    void* __restrict__ Cout, int K, int Nld, int nout){
  __shared__ unsigned short As[128*40];
  __shared__ unsigned short Bs[64*40];
  int t = threadIdx.x;
  int bm = blockIdx.y, bn = blockIdx.x;
  int arow = t >> 1, ahalf = t & 1;
  int gm = bm*128 + arow;
  const unsigned short* abase;
  if(MODE == 0){
    abase = A + (size_t)gm*K + ahalf*16;
  } else if(MODE == 1){
    int n = gm/81; int r = gm - n*81; int oh = r/9; int ow = r - oh*9;
    abase = A + (((size_t)n*20 + 2*oh)*20 + 2*ow)*32 + ahalf*16;
  } else if(MODE == 2){
    int n = gm/49; int r = gm - n*49; int oh = r/7; int ow = r - oh*7;
    abase = A + (((size_t)n*9 + oh)*9 + ow)*64 + ahalf*16;
  } else {
    int n = gm/400; int r = gm - n*400; int oh = r/20; int ow = r - oh*20;
    abase = A + (size_t)n*7056 + (size_t)(oh*4)*84 + ow*4;
  }
  int brow = t >> 2, bq = t & 3;
  const unsigned short* bbase = B + (size_t)(bn*64 + brow)*K + bq*8;
  int l = t & 63, w = t >> 6;
  int wr = w >> 1, wc = w & 1;
  int lr = l & 15, lk = (l >> 4)*8;
  f32x4 acc[4][2] = {};
  int nsteps = K >> 5;
  for(int s=0; s<nsteps; s++){
    if(MODE == 3){
      const unsigned short* src = abase + (size_t)(s*4 + ahalf*2)*84;
      s4v p0 = *(const s4v*)src;
      s4v p1 = *(const s4v*)(src + 4);
      s4v p2 = *(const s4v*)(src + 84);
      s4v p3 = *(const s4v*)(src + 88);
      *(s4v*)&As[arow*40 + ahalf*16]      = p0;
      *(s4v*)&As[arow*40 + ahalf*16 + 4]  = p1;
      *(s4v*)&As[arow*40 + ahalf*16 + 8]  = p2;
      *(s4v*)&As[arow*40 + ahalf*16 + 12] = p3;
    } else {
      const unsigned short* src;
      if(MODE == 0){
        src = abase + s*32;
      } else if(MODE == 1){
        int kh = s >> 2, kw = s & 3;
        src = abase + (kh*20 + kw)*32;
      } else {
        int khw = s >> 1; int kh = khw/3; int kw = khw - kh*3;
        src = abase + (kh*9 + kw)*64 + (s & 1)*32;
      }
      bf16x8 a0 = *(const bf16x8*)src;
      bf16x8 a1 = *(const bf16x8*)(src + 8);
      *(bf16x8*)&As[arow*40 + ahalf*16] = a0;
      *(bf16x8*)&As[arow*40 + ahalf*16 + 8] = a1;
    }
    bf16x8 bv = *(const bf16x8*)(bbase + s*32);
    *(bf16x8*)&Bs[brow*40 + bq*8] = bv;
    __syncthreads();
    bf16x8 af[4];
    #pragma unroll
    for(int mf=0; mf<4; mf++)
      af[mf] = *(const bf16x8*)&As[(wr*64 + mf*16 + lr)*40 + lk];
    bf16x8 b0 = *(const bf16x8*)&Bs[(wc*32 + lr)*40 + lk];
    bf16x8 b1 = *(const bf16x8*)&Bs[(wc*32 + 16 + lr)*40 + lk];
    #pragma unroll
    for(int mf=0; mf<4; mf++){
      acc[mf][0] = __builtin_amdgcn_mfma_f32_16x16x32_bf16(af[mf], b0, acc[mf][0], 0, 0, 0);
      acc[mf][1] = __builtin_amdgcn_mfma_f32_16x16x32_bf16(af[mf], b1, acc[mf][1], 0, 0, 0);
    }
    __syncthreads();
  }
  #pragma unroll
  for(int nf=0; nf<2; nf++){
    int gcol = bn*64 + wc*32 + nf*16 + lr;
    if(gcol >= nout) continue;
    float bb = bias1[gcol] + (bias2 ? bias2[gcol] : 0.f);
    #pragma unroll
    for(int mf=0; mf<4; mf++){
      #pragma unroll
      for(int reg=0; reg<4; reg++){
        int grow = bm*128 + wr*64 + mf*16 + (l>>4)*4 + reg;
        float v = acc[mf][nf][reg] + bb;
        if(RELU) v = v>0.f ? v : 0.f;
        if(OUTBF16) ((unsigned short*)Cout)[(size_t)grow*Nld + gcol] = f2bf(v);
        else        ((float*)Cout)[(size_t)grow*Nld + gcol] = v;
      }
    }
  }
}

// ================= LSTM scan, MFMA + async gx pipeline =====================
// 2 blocks x 512 thr (8 waves); block owns 16 batch. D[gatecol][batch] = W_hh·h:
// A=W frags (VGPR-resident), B=h frags (LDS, bf16, dbuf). Lane (w,lg,lr) owns
// units u0=16w+lg*4..+3 for batch lr, all 4 gates -> fully register tail,
// dwordx4 hs store, b64 hA write. gx staged in LDS (3 slots) via
// global_load_lds, raw s_barrier + counted vmcnt (loads span barriers).
#define GXP 524   // padded row: 524%32=12 -> 2-way bank aliasing (free)
__global__ __launch_bounds__(512) void lstm_mfma2_k(
    const float* __restrict__ gx,   // [4096][512] f32
    const float* __restrict__ done,
    const float* __restrict__ h0, const float* __restrict__ c0,
    const unsigned short* __restrict__ whhc,
    float* __restrict__ hs, float* __restrict__ out_hT, float* __restrict__ out_cT){
  __shared__ float mask_lds[TT*16];                         // 8 KB
  __shared__ unsigned short hA[2][16][152];                 // 9.5 KB
  __shared__ __align__(16) float gxS[3][16][GXP];           // 98.3 KB
  int t0 = threadIdx.x;
  int B0 = blockIdx.x * 16;
  int w = t0 >> 6, l = t0 & 63;
  int lr = l & 15, lg = l >> 4;
  int ucol = 16*w + lr;        // W row within gate block
  int u0 = 16*w + lg*4;        // tail unit base

  // W_hh A-fragments: row = g*128+ucol, k = kt*32+lg*8
  bf16x8 wA[4][4];
  #pragma unroll
  for(int g=0; g<4; g++)
    #pragma unroll
    for(int kt=0; kt<4; kt++)
      wA[g][kt] = *(const bf16x8*)&whhc[(size_t)(g*128 + ucol)*128 + kt*32 + lg*8];

  // stage (1-done) masks
  for(int i=t0; i<TT*16; i+=512){
    int tt = i >> 4, bb = i & 15;
    mask_lds[i] = 1.f - done[tt*32 + B0 + bb];
  }
  // init c (regs) + hA[0] = h0 * mask(0)
  f4 cv = *(const f4*)&c0[(size_t)(B0+lr)*128 + u0];
  f4 h0v = *(const f4*)&h0[(size_t)(B0+lr)*128 + u0];
  {
    float m0 = 1.f - done[0*BB + B0 + lr];
    s4v hp;
    #pragma unroll
    for(int r=0;r<4;r++) hp[r] = (short)f2bf(h0v[r]*m0);
    *(s4v*)&hA[0][lr][u0] = hp;
  }
  // prologue: DMA slots 0,1 (wave w does chunks w+8j; chunk c: b=c>>1, half=c&1)
  #pragma unroll
  for(int sl=0; sl<2; sl++)
    #pragma unroll
    for(int j=0; j<4; j++){
      int cch = w + 8*j; int b = cch >> 1, half = cch & 1;
      gload_lds16(gx + ((size_t)(sl*32 + B0 + b))*512 + half*256 + l*4,
                  &gxS[sl][b][half*256]);
    }
  __syncthreads();   // drains vmcnt(0): masks, hA0, slots 0&1 ready

  f4 hout;
  for(int t=0; t<TT; t++){
    int cur = t & 1, slot = t % 3;
    // ph1: issue DMA for step t+2 into slot (t+2)%3 (dup last step if beyond)
    {
      int ts = (t+2 < TT) ? t+2 : TT-1;
      int s2 = (t+2) % 3;
      #pragma unroll
      for(int j=0; j<4; j++){
        int cch = w + 8*j; int b = cch >> 1, half = cch & 1;
        gload_lds16(gx + ((size_t)(ts*32 + B0 + b))*512 + half*256 + l*4,
                    &gxS[s2][b][half*256]);
      }
    }
    // ph2: ds reads (slot t guaranteed complete by prev-step vmcnt + barrier)
    bf16x8 hF[4];
    #pragma unroll
    for(int kt=0; kt<4; kt++)
      hF[kt] = *(const bf16x8*)&hA[cur][lr][kt*32 + lg*8];
    f4 gxv[4];
    #pragma unroll
    for(int g=0; g<4; g++)
      gxv[g] = *(const f4*)&gxS[slot][lr][g*128 + u0];
    f32x4 acc[4] = {};
    #pragma unroll
    for(int kt=0; kt<4; kt++)
      #pragma unroll
      for(int g=0; g<4; g++)
        acc[g] = __builtin_amdgcn_mfma_f32_16x16x32_bf16(wA[g][kt], hF[kt], acc[g], 0, 0, 0);
    // tail: 4 cells/lane, all registers
    float m  = mask_lds[t*16 + lr];
    float mn = (t < TT-1) ? mask_lds[(t+1)*16 + lr] : 1.f;
    s4v hp;
    #pragma unroll
    for(int r=0; r<4; r++){
      float iv = fsig (acc[0][r] + gxv[0][r]);
      float fv = fsig (acc[1][r] + gxv[1][r]);
      float gv = ftanh(acc[2][r] + gxv[2][r]);
      float ov = fsig (acc[3][r] + gxv[3][r]);
      float cn = fv*(cv[r]*m) + iv*gv;
      float hn = ov*ftanh(cn);
      cv[r] = cn; hout[r] = hn;
      hp[r] = (short)f2bf(hn*mn);
    }
    *(f4*)&hs[((size_t)t*BB + B0 + lr)*128 + u0] = hout;
    *(s4v*)&hA[cur^1][lr][u0] = hp;
    // ph3: counted waits + raw barrier (keep t+2 loads + last store in flight)
    asm volatile("s_waitcnt vmcnt(6) lgkmcnt(0)" ::: "memory");
    __builtin_amdgcn_s_barrier();
  }
  *(f4*)&out_hT[(size_t)(B0+lr)*128 + u0] = hout;
  *(f4*)&out_cT[(size_t)(B0+lr)*128 + u0] = cv;
}

// ================= heads ===================================================
__global__ __launch_bounds__(256) void heads_k(const float* __restrict__ hs,
    const float* __restrict__ Wa, const float* __restrict__ ba,
    const float* __restrict__ Wc, const float* __restrict__ bc,
    float* __restrict__ out){
  int gid = blockIdx.x*256 + threadIdx.x;  // 4096*7
  int n = gid/7, a = gid - n*7;
  const float* w = (a<6) ? (Wa + a*128) : Wc;
  float bias = (a<6) ? ba[a] : bc[0];
  const float* h = hs + (size_t)n*128;
  float acc = 0.f;
  #pragma unroll
  for(int k=0;k<32;k++){
    f4 hv = *(const f4*)(h + k*4);
    f4 wv = *(const f4*)(w + k*4);
    acc += hv[0]*wv[0]+hv[1]*wv[1]+hv[2]*wv[2]+hv[3]*wv[3];
  }
  float v = acc + bias;
  if(a<6) out[(size_t)n*6 + a] = v;
  else    out[24576 + n] = v;
}

extern "C" void kernel_launch(void* const* d_in, const int* in_sizes, int n_in,
                              void* d_out, int out_size, void* d_ws, size_t ws_size,
                              hipStream_t stream){
  const float* x    = (const float*)d_in[0];
  const float* done = (const float*)d_in[1];
  const float* h0   = (const float*)d_in[2];
  const float* c0   = (const float*)d_in[3];
  const float* W1   = (const float*)d_in[4];
  const float* b1   = (const float*)d_in[5];
  const float* W2   = (const float*)d_in[6];
  const float* b2   = (const float*)d_in[7];
  const float* W3   = (const float*)d_in[8];
  const float* b3   = (const float*)d_in[9];
  const float* Wfc  = (const float*)d_in[10];
  const float* bfc  = (const float*)d_in[11];
  const float* W_ih = (const float*)d_in[12];
  const float* W_hh = (const float*)d_in[13];
  const float* b_ih = (const float*)d_in[14];
  const float* b_hh = (const float*)d_in[15];
  const float* Wa   = (const float*)d_in[16];
  const float* ba   = (const float*)d_in[17];
  const float* Wc   = (const float*)d_in[18];
  const float* bc   = (const float*)d_in[19];
  float* out = (float*)d_out;

  char* ws = (char*)d_ws;
  // region plan (bytes), stream-ordered reuse:
  //  z1 NHWC   [0, 104857600)           xb16 [104857600, 162660352)
  //  z2 NHWC   [104857600, 147324928)   (reuses dead xb16)
  //  z3 NHWC   [0, 25690112)            (reuses dead z1)
  //  hid       [25690112, 29884416)
  //  gx        [29884416, 38273024)     [n][512] f32
  //  hs        [38273024, 40370176)
  //  weights   [162660352,...) end 166674432
  unsigned short* z1   = (unsigned short*)(ws + 0);
  unsigned short* xb16 = (unsigned short*)(ws + 104857600);
  unsigned short* z2   = (unsigned short*)(ws + 104857600);
  unsigned short* z3   = (unsigned short*)(ws + 0);
  unsigned short* hid  = (unsigned short*)(ws + 25690112);
  float* gx            = (float*)(ws + 29884416);
  float* hs            = (float*)(ws + 38273024);
  unsigned short* w2c  = (unsigned short*)(ws + 162660352);
  unsigned short* w3c  = (unsigned short*)(ws + 162725888);
  unsigned short* wfcc = (unsigned short*)(ws + 162799616);
  unsigned short* wihc = (unsigned short*)(ws + 166010880);
  unsigned short* w1c  = (unsigned short*)(ws + 166535168);
  unsigned short* whhc = (unsigned short*)(ws + 166543360);

  prep_w1 <<<16,  256, 0, stream>>>(W1, w1c);
  prep_w2 <<<128, 256, 0, stream>>>(W2, w2c);
  prep_w3 <<<144, 256, 0, stream>>>(W3, w3c);
  prep_wfc<<<6272,256, 0, stream>>>(Wfc, wfcc);
  prep_wih<<<1024,256, 0, stream>>>(W_ih, wihc);
  prep_whh<<<256, 256, 0, stream>>>(W_hh, whhc);
  prep_x  <<<14112,256,0, stream>>>(x, xb16);

  // conv1: M=4096*400, N=32(pad 64), K=64
  mgemm_k<3,1,1><<<dim3(1,12800),256,0,stream>>>(xb16, w1c, b1, nullptr, z1, 64, 32, 32);
  // conv2: M=4096*81, N=64, K=512
  mgemm_k<1,1,1><<<dim3(1,2592),256,0,stream>>>(z1, w2c, b2, nullptr, z2, 512, 64, 64);
  // conv3: M=4096*49, N=64, K=576
  mgemm_k<2,1,1><<<dim3(1,1568),256,0,stream>>>(z2, w3c, b3, nullptr, z3, 576, 64, 64);
  // FC: M=4096, N=512, K=3136 -> hid bf16 relu
  mgemm_k<0,1,1><<<dim3(8,32),256,0,stream>>>(z3, wfcc, bfc, nullptr, hid, 3136, 512, 512);
  // gates: M=4096, N=512, K=512 -> gx f32 row-major
  mgemm_k<0,0,0><<<dim3(8,32),256,0,stream>>>(hid, wihc, b_ih, b_hh, gx, 512, 512, 512);

  lstm_mfma2_k<<<2,512,0,stream>>>(gx, done, h0, c0, whhc, hs, out+28672, out+32768);
  heads_k<<<112,256,0,stream>>>(hs, Wa, ba, Wc, bc, out);
}

// Round 6
// 360.180 us; speedup vs baseline: 1.2108x; 1.2108x over previous
//
#include <hip/hip_runtime.h>

#define TT 128
#define BB 32
#define NN (TT*BB)   // 4096

typedef float f4 __attribute__((ext_vector_type(4)));
typedef float f32x4 __attribute__((ext_vector_type(4)));
typedef short s8 __attribute__((ext_vector_type(8)));
typedef short bf16x8 __attribute__((ext_vector_type(8)));
typedef short s4v __attribute__((ext_vector_type(4)));

__device__ __forceinline__ float bf2f(unsigned short u){
  union{unsigned int i; float f;} x; x.i = ((unsigned int)u)<<16; return x.f;
}
__device__ __forceinline__ unsigned short f2bf(float f){
  union{float ff; unsigned int i;} x; x.ff=f;
  unsigned int r = x.i + 0x7FFFu + ((x.i>>16)&1u);
  return (unsigned short)(r>>16);
}
// NaN-safe fast sigmoid/tanh
__device__ __forceinline__ float fsig(float x){
  return __builtin_amdgcn_rcpf(1.f + __expf(-x));
}
__device__ __forceinline__ float ftanh(float x){
  return 1.f - 2.f*__builtin_amdgcn_rcpf(1.f + __expf(2.f*x));
}
// async global(16B contiguous per lane) -> LDS (wave-uniform base + lane*16)
__device__ __forceinline__ void gload_lds16(const void* g, void* lds){
  __builtin_amdgcn_global_load_lds(
    (const __attribute__((address_space(1))) unsigned int*)g,
    (__attribute__((address_space(3))) unsigned int*)lds, 16, 0, 0);
}

// ================= weight prep =============================================
__global__ __launch_bounds__(256) void prep_w1(const float* __restrict__ W1,
    unsigned short* __restrict__ w1c){
  int i = blockIdx.x*256 + threadIdx.x;       // 4096
  int co = i >> 6; int k = i & 63;
  w1c[i] = (co < 32) ? f2bf(W1[co*64 + k] * (1.f/255.f)) : (unsigned short)0;
}
__global__ __launch_bounds__(256) void prep_w2(const float* __restrict__ W2,
    unsigned short* __restrict__ w2c){
  int i = blockIdx.x*256 + threadIdx.x;       // 32768
  int co = i >> 9; int rem = i & 511; int khw = rem >> 5; int ci = rem & 31;
  w2c[i] = f2bf(W2[(co*32 + ci)*16 + khw]);
}
__global__ __launch_bounds__(256) void prep_w3(const float* __restrict__ W3,
    unsigned short* __restrict__ w3c){
  int i = blockIdx.x*256 + threadIdx.x;       // 36864
  int co = i/576; int rem = i - co*576; int khw = rem >> 6; int ci = rem & 63;
  w3c[i] = f2bf(W3[(co*64 + ci)*9 + khw]);
}
__global__ __launch_bounds__(256) void prep_wfc(const float* __restrict__ Wfc,
    unsigned short* __restrict__ wfcc){
  int i = blockIdx.x*256 + threadIdx.x;       // 1605632
  int nn = i/3136; int rem = i - nn*3136; int sp = rem >> 6; int ci = rem & 63;
  wfcc[i] = f2bf(Wfc[nn*3136 + ci*49 + sp]);
}
__global__ __launch_bounds__(256) void prep_wih(const float* __restrict__ W_ih,
    unsigned short* __restrict__ wihc){
  int i = blockIdx.x*256 + threadIdx.x;       // 262144
  wihc[i] = f2bf(W_ih[i]);
}
__global__ __launch_bounds__(256) void prep_whh(const float* __restrict__ W_hh,
    unsigned short* __restrict__ whhc){
  int i = blockIdx.x*256 + threadIdx.x;       // 65536
  whhc[i] = f2bf(W_hh[i]);
}
__global__ __launch_bounds__(256) void prep_x(const float* __restrict__ x,
    unsigned short* __restrict__ xb){
  int i = blockIdx.x*256 + threadIdx.x;       // 3,612,672
  f4 v0 = *(const f4*)(x + (size_t)i*8);
  f4 v1 = *(const f4*)(x + (size_t)i*8 + 4);
  s8 o;
  #pragma unroll
  for(int j=0;j<4;j++){ o[j] = (short)f2bf(v0[j]); o[4+j] = (short)f2bf(v1[j]); }
  *(s8*)&xb[(size_t)i*8] = o;
}

// ================= unified MFMA GEMM =======================================
// C[M,N] = act(A[M,K]*B[N,K]^T + bias1 (+bias2)); A bf16 (gathered), B bf16 [N][K].
// BM=128, BN=64, BK=32. 256 threads = 4 waves (2x2), wave tile 64x32.
template<int MODE, int OUTBF16, int RELU>
__global__ __launch_bounds__(256) void mgemm_k(
    const unsigned short* __restrict__ A, const unsigned short* __restrict__ B,
    const float* __restrict__ bias1, const float* __restrict__ bias2,
    void* __restrict__ Cout, int K, int Nld, int nout){
  __shared__ unsigned short As[128*40];
  __shared__ unsigned short Bs[64*40];
  int t = threadIdx.x;
  int bm = blockIdx.y, bn = blockIdx.x;
  int arow = t >> 1, ahalf = t & 1;
  int gm = bm*128 + arow;
  const unsigned short* abase;
  if(MODE == 0){
    abase = A + (size_t)gm*K + ahalf*16;
  } else if(MODE == 1){
    int n = gm/81; int r = gm - n*81; int oh = r/9; int ow = r - oh*9;
    abase = A + (((size_t)n*20 + 2*oh)*20 + 2*ow)*32 + ahalf*16;
  } else if(MODE == 2){
    int n = gm/49; int r = gm - n*49; int oh = r/7; int ow = r - oh*7;
    abase = A + (((size_t)n*9 + oh)*9 + ow)*64 + ahalf*16;
  } else {
    int n = gm/400; int r = gm - n*400; int oh = r/20; int ow = r - oh*20;
    abase = A + (size_t)n*7056 + (size_t)(oh*4)*84 + ow*4;
  }
  int brow = t >> 2, bq = t & 3;
  const unsigned short* bbase = B + (size_t)(bn*64 + brow)*K + bq*8;
  int l = t & 63, w = t >> 6;
  int wr = w >> 1, wc = w & 1;
  int lr = l & 15, lk = (l >> 4)*8;
  f32x4 acc[4][2] = {};
  int nsteps = K >> 5;
  for(int s=0; s<nsteps; s++){
    if(MODE == 3){
      const unsigned short* src = abase + (size_t)(s*4 + ahalf*2)*84;
      s4v p0 = *(const s4v*)src;
      s4v p1 = *(const s4v*)(src + 4);
      s4v p2 = *(const s4v*)(src + 84);
      s4v p3 = *(const s4v*)(src + 88);
      *(s4v*)&As[arow*40 + ahalf*16]      = p0;
      *(s4v*)&As[arow*40 + ahalf*16 + 4]  = p1;
      *(s4v*)&As[arow*40 + ahalf*16 + 8]  = p2;
      *(s4v*)&As[arow*40 + ahalf*16 + 12] = p3;
    } else {
      const unsigned short* src;
      if(MODE == 0){
        src = abase + s*32;
      } else if(MODE == 1){
        int kh = s >> 2, kw = s & 3;
        src = abase + (kh*20 + kw)*32;
      } else {
        int khw = s >> 1; int kh = khw/3; int kw = khw - kh*3;
        src = abase + (kh*9 + kw)*64 + (s & 1)*32;
      }
      bf16x8 a0 = *(const bf16x8*)src;
      bf16x8 a1 = *(const bf16x8*)(src + 8);
      *(bf16x8*)&As[arow*40 + ahalf*16] = a0;
      *(bf16x8*)&As[arow*40 + ahalf*16 + 8] = a1;
    }
    bf16x8 bv = *(const bf16x8*)(bbase + s*32);
    *(bf16x8*)&Bs[brow*40 + bq*8] = bv;
    __syncthreads();
    bf16x8 af[4];
    #pragma unroll
    for(int mf=0; mf<4; mf++)
      af[mf] = *(const bf16x8*)&As[(wr*64 + mf*16 + lr)*40 + lk];
    bf16x8 b0 = *(const bf16x8*)&Bs[(wc*32 + lr)*40 + lk];
    bf16x8 b1 = *(const bf16x8*)&Bs[(wc*32 + 16 + lr)*40 + lk];
    #pragma unroll
    for(int mf=0; mf<4; mf++){
      acc[mf][0] = __builtin_amdgcn_mfma_f32_16x16x32_bf16(af[mf], b0, acc[mf][0], 0, 0, 0);
      acc[mf][1] = __builtin_amdgcn_mfma_f32_16x16x32_bf16(af[mf], b1, acc[mf][1], 0, 0, 0);
    }
    __syncthreads();
  }
  #pragma unroll
  for(int nf=0; nf<2; nf++){
    int gcol = bn*64 + wc*32 + nf*16 + lr;
    if(gcol >= nout) continue;
    float bb = bias1[gcol] + (bias2 ? bias2[gcol] : 0.f);
    #pragma unroll
    for(int mf=0; mf<4; mf++){
      #pragma unroll
      for(int reg=0; reg<4; reg++){
        int grow = bm*128 + wr*64 + mf*16 + (l>>4)*4 + reg;
        float v = acc[mf][nf][reg] + bb;
        if(RELU) v = v>0.f ? v : 0.f;
        if(OUTBF16) ((unsigned short*)Cout)[(size_t)grow*Nld + gcol] = f2bf(v);
        else        ((float*)Cout)[(size_t)grow*Nld + gcol] = v;
      }
    }
  }
}

// ================= LSTM scan v3: 8 blocks x 4 batch ========================
// 8 blocks x 512 thr (8 waves); block owns batch [4*bid, 4*bid+4). Per step:
//  MFMA D[gatecol][batch] = W_hh·h  (wave w covers units 16w..16w+16, 4 gates)
//  -> lanes lr<4 scatter acc frags to per-wave LDS gW[u16][b4][g4]
//  -> lgkmcnt(0) (same-wave) -> every lane gathers ITS cell (1 cell/lane!)
//  -> tail (10 trans/lane) -> hA write + hs store.
// gx staged via 3-slot global_load_lds pipeline, vmcnt(3), raw s_barrier.
__global__ __launch_bounds__(512) void lstm_v3_k(
    const float* __restrict__ gx,   // [4096][512] f32
    const float* __restrict__ done,
    const float* __restrict__ h0, const float* __restrict__ c0,
    const unsigned short* __restrict__ whhc,
    float* __restrict__ hs, float* __restrict__ out_hT, float* __restrict__ out_cT){
  __shared__ float mask_lds[TT*4];                 // 2 KB  [t][b]
  __shared__ unsigned short hA[2][4][136];         // h bf16, dbuf, pad 136
  __shared__ __align__(16) float gxS[3][4][520];   // 24.96 KB  [slot][b][512+pad]
  __shared__ __align__(16) float gW[8][256];       // 8 KB  per-wave [u16][b4][g4]
  int tid = threadIdx.x;
  int B0 = blockIdx.x * 4;
  int w = tid >> 6, l = tid & 63;
  int lr = l & 15, lg = l >> 4;
  int cu = 16*w + (l >> 2);    // this lane's cell: unit 0..127
  int cb = l & 3;              //                   batch 0..3
  int drow = w >> 1, dhalf = w & 1;   // DMA: wave stages gx row drow, half dhalf

  // W_hh A-frags: row = g*128 + (16w+lr), k = kt*32 + lg*8
  bf16x8 wA[4][4];
  #pragma unroll
  for(int g=0; g<4; g++)
    #pragma unroll
    for(int kt=0; kt<4; kt++)
      wA[g][kt] = *(const bf16x8*)&whhc[(size_t)(g*128 + 16*w + lr)*128 + kt*32 + lg*8];

  // stage (1-done) masks: 512 entries, one per thread
  {
    int tt = tid >> 2, bb = tid & 3;
    mask_lds[tid] = 1.f - done[tt*32 + B0 + bb];
  }
  // init: c in regs (raw), hA[0] = h0 * mask(0)   (1 cell/thread)
  float cv = c0[(size_t)(B0+cb)*128 + cu];
  float hv0 = h0[(size_t)(B0+cb)*128 + cu];
  float hout = 0.f;
  {
    float m0 = 1.f - done[0*BB + B0 + cb];
    hA[0][cb][cu] = f2bf(hv0 * m0);
  }
  // prologue DMA: slots 0,1 (1 instr/wave/slot)
  #pragma unroll
  for(int sl=0; sl<2; sl++)
    gload_lds16(gx + ((size_t)(sl*32 + B0 + drow))*512 + dhalf*256 + l*4,
                &gxS[sl][drow][dhalf*256]);
  __syncthreads();   // one-time full drain: masks, hA0, slots 0&1 ready

  int slot = 0;
  for(int t=0; t<TT; t++){
    int cur = t & 1;
    // ph0: issue DMA for step t+2 into slot (slot+2)%3
    {
      int ts = (t+2 < TT) ? t+2 : TT-1;
      int s2 = (slot >= 1) ? slot-1 : 2;
      gload_lds16(gx + ((size_t)(ts*32 + B0 + drow))*512 + dhalf*256 + l*4,
                  &gxS[s2][drow][dhalf*256]);
    }
    // ph1: h frags + MFMA (batch cols >=4 are garbage, discarded)
    bf16x8 hF[4];
    #pragma unroll
    for(int kt=0; kt<4; kt++)
      hF[kt] = *(const bf16x8*)&hA[cur][lr & 3][kt*32 + lg*8];
    f32x4 acc[4] = {};
    #pragma unroll
    for(int kt=0; kt<4; kt++)
      #pragma unroll
      for(int g=0; g<4; g++)
        acc[g] = __builtin_amdgcn_mfma_f32_16x16x32_bf16(wA[g][kt], hF[kt], acc[g], 0, 0, 0);
    // ph2: scatter gates to per-wave region (only valid batch lanes)
    if(lr < 4){
      #pragma unroll
      for(int g=0; g<4; g++)
        #pragma unroll
        for(int r=0; r<4; r++)
          gW[w][(lg*4 + r)*16 + lr*4 + g] = acc[g][r];
    }
    asm volatile("s_waitcnt lgkmcnt(0)" ::: "memory");
    // ph3: gather own cell (lane-linear b128) + gx + tail
    f4 g4 = *(const f4*)&gW[w][l*4];   // [i,f,g,o] for (cu,cb)
    float gx0 = gxS[slot][cb][      cu];
    float gx1 = gxS[slot][cb][128 + cu];
    float gx2 = gxS[slot][cb][256 + cu];
    float gx3 = gxS[slot][cb][384 + cu];
    float m  = mask_lds[t*4 + cb];
    float mn = (t < TT-1) ? mask_lds[(t+1)*4 + cb] : 1.f;
    float iv = fsig (g4[0] + gx0);
    float fv = fsig (g4[1] + gx1);
    float gv = ftanh(g4[2] + gx2);
    float ov = fsig (g4[3] + gx3);
    float cn = fv*(cv*m) + iv*gv;
    float hn = ov*ftanh(cn);
    cv = cn; hout = hn;
    hs[((size_t)t*BB + B0 + cb)*128 + cu] = hn;
    hA[cur^1][cb][cu] = f2bf(hn * mn);
    // ph4: counted vmcnt (keep t's DMA+store, t-1's store in flight) + barrier
    asm volatile("s_waitcnt vmcnt(3) lgkmcnt(0)" ::: "memory");
    __builtin_amdgcn_s_barrier();
    slot = (slot >= 2) ? 0 : slot+1;
  }
  out_hT[(size_t)(B0+cb)*128 + cu] = hout;
  out_cT[(size_t)(B0+cb)*128 + cu] = cv;
}

// ================= heads ===================================================
__global__ __launch_bounds__(256) void heads_k(const float* __restrict__ hs,
    const float* __restrict__ Wa, const float* __restrict__ ba,
    const float* __restrict__ Wc, const float* __restrict__ bc,
    float* __restrict__ out){
  int gid = blockIdx.x*256 + threadIdx.x;  // 4096*7
  int n = gid/7, a = gid - n*7;
  const float* w = (a<6) ? (Wa + a*128) : Wc;
  float bias = (a<6) ? ba[a] : bc[0];
  const float* h = hs + (size_t)n*128;
  float acc = 0.f;
  #pragma unroll
  for(int k=0;k<32;k++){
    f4 hv = *(const f4*)(h + k*4);
    f4 wv = *(const f4*)(w + k*4);
    acc += hv[0]*wv[0]+hv[1]*wv[1]+hv[2]*wv[2]+hv[3]*wv[3];
  }
  float v = acc + bias;
  if(a<6) out[(size_t)n*6 + a] = v;
  else    out[24576 + n] = v;
}

extern "C" void kernel_launch(void* const* d_in, const int* in_sizes, int n_in,
                              void* d_out, int out_size, void* d_ws, size_t ws_size,
                              hipStream_t stream){
  const float* x    = (const float*)d_in[0];
  const float* done = (const float*)d_in[1];
  const float* h0   = (const float*)d_in[2];
  const float* c0   = (const float*)d_in[3];
  const float* W1   = (const float*)d_in[4];
  const float* b1   = (const float*)d_in[5];
  const float* W2   = (const float*)d_in[6];
  const float* b2   = (const float*)d_in[7];
  const float* W3   = (const float*)d_in[8];
  const float* b3   = (const float*)d_in[9];
  const float* Wfc  = (const float*)d_in[10];
  const float* bfc  = (const float*)d_in[11];
  const float* W_ih = (const float*)d_in[12];
  const float* W_hh = (const float*)d_in[13];
  const float* b_ih = (const float*)d_in[14];
  const float* b_hh = (const float*)d_in[15];
  const float* Wa   = (const float*)d_in[16];
  const float* ba   = (const float*)d_in[17];
  const float* Wc   = (const float*)d_in[18];
  const float* bc   = (const float*)d_in[19];
  float* out = (float*)d_out;

  char* ws = (char*)d_ws;
  // region plan (bytes), stream-ordered reuse:
  //  z1 NHWC   [0, 104857600)           xb16 [104857600, 162660352)
  //  z2 NHWC   [104857600, 147324928)   (reuses dead xb16)
  //  z3 NHWC   [0, 25690112)            (reuses dead z1)
  //  hid       [25690112, 29884416)
  //  gx        [29884416, 38273024)     [n][512] f32
  //  hs        [38273024, 40370176)
  //  weights   [162660352,...) end 166674432
  unsigned short* z1   = (unsigned short*)(ws + 0);
  unsigned short* xb16 = (unsigned short*)(ws + 104857600);
  unsigned short* z2   = (unsigned short*)(ws + 104857600);
  unsigned short* z3   = (unsigned short*)(ws + 0);
  unsigned short* hid  = (unsigned short*)(ws + 25690112);
  float* gx            = (float*)(ws + 29884416);
  float* hs            = (float*)(ws + 38273024);
  unsigned short* w2c  = (unsigned short*)(ws + 162660352);
  unsigned short* w3c  = (unsigned short*)(ws + 162725888);
  unsigned short* wfcc = (unsigned short*)(ws + 162799616);
  unsigned short* wihc = (unsigned short*)(ws + 166010880);
  unsigned short* w1c  = (unsigned short*)(ws + 166535168);
  unsigned short* whhc = (unsigned short*)(ws + 166543360);

  prep_w1 <<<16,  256, 0, stream>>>(W1, w1c);
  prep_w2 <<<128, 256, 0, stream>>>(W2, w2c);
  prep_w3 <<<144, 256, 0, stream>>>(W3, w3c);
  prep_wfc<<<6272,256, 0, stream>>>(Wfc, wfcc);
  prep_wih<<<1024,256, 0, stream>>>(W_ih, wihc);
  prep_whh<<<256, 256, 0, stream>>>(W_hh, whhc);
  prep_x  <<<14112,256,0, stream>>>(x, xb16);

  // conv1: M=4096*400, N=32(pad 64), K=64
  mgemm_k<3,1,1><<<dim3(1,12800),256,0,stream>>>(xb16, w1c, b1, nullptr, z1, 64, 32, 32);
  // conv2: M=4096*81, N=64, K=512
  mgemm_k<1,1,1><<<dim3(1,2592),256,0,stream>>>(z1, w2c, b2, nullptr, z2, 512, 64, 64);
  // conv3: M=4096*49, N=64, K=576
  mgemm_k<2,1,1><<<dim3(1,1568),256,0,stream>>>(z2, w3c, b3, nullptr, z3, 576, 64, 64);
  // FC: M=4096, N=512, K=3136 -> hid bf16 relu
  mgemm_k<0,1,1><<<dim3(8,32),256,0,stream>>>(z3, wfcc, bfc, nullptr, hid, 3136, 512, 512);
  // gates: M=4096, N=512, K=512 -> gx f32 row-major
  mgemm_k<0,0,0><<<dim3(8,32),256,0,stream>>>(hid, wihc, b_ih, b_hh, gx, 512, 512, 512);

  lstm_v3_k<<<8,512,0,stream>>>(gx, done, h0, c0, whhc, hs, out+28672, out+32768);
  heads_k<<<112,256,0,stream>>>(hs, Wa, ba, Wc, bc, out);
}